// Round 15
// baseline (30.548 us; speedup 1.0000x reference)
//
#include <hip/hip_runtime.h>

// QuantHotLowRank: out[n][d] = sum_r Uq[ids[n]][r] * Bq[r][d]
// K=200000, R=64, D=1024, N=16384, 4-bit groupwise fake-quant, group=32.
//
// Two kernels. Cost model from R11/R13/R14: quant-element pipeline ~0.65us
// per MILLION elements (dominated by amax/clamp/DP-mul/bf16-split, not the
// divide). R7 re-quantized every U row 8x (8.4M quants ~5us). This round:
// each gemm block owns TWO col-slices and quantizes its A rows ONCE, reusing
// the register fragments -> A-redundancy 4x. Plus R14's guarded quant
// (SP rint decision, fp64 only within 1e-4 of half-integer boundaries;
// q = n*scale_d always fp64 -> decisions bit-identical to numpy).
//
// Ledger: coop grid-sync 5.7x worse (R9); in-gemm B-requant -1.7us (R11);
// zero-LDS VGPR32 -25us (R12); BN=64/8-blk-CU -5.4us (R13, the 16x A-quant
// datapoint); BM=128 / nt stores / LDS-transpose neutral (R10/R6/R4).

#define R_DIM 64
#define D_DIM 1024
#define N_IDS 16384

#define BM 64          // rows per tile (4 waves x 16)
#define BN 128         // cols per slice
#define NSLICE 2       // col-slices per block
#define LDS_STRIDE 72  // ushorts per B-LDS row: 64 + 8 pad
#define OT_STRIDE 132  // floats per out-LDS row: 128 + 4 pad

typedef __attribute__((ext_vector_type(8))) __bf16 bf16x8;
typedef __attribute__((ext_vector_type(4))) float f32x4;

__device__ inline unsigned short f32_to_bf16_rne(float f) {
  union { float f; unsigned int u; } c; c.f = f;
  unsigned int u = c.u;
  u += 0x7fffu + ((u >> 16) & 1u);   // round-to-nearest-even (finite inputs only)
  return (unsigned short)(u >> 16);
}

__device__ inline float bf16_bits_to_f32(unsigned short h) {
  union { unsigned int u; float f; } c; c.u = ((unsigned int)h) << 16;
  return c.f;
}

// Guarded fake-quant: SP fast path for the rint decision, fp64 only within
// 1e-4 of a half-integer boundary; q = n*scale_d in fp64 (bit-exact to np).
__device__ inline void quant_elem_g(float w, float rcp32, double scale_d,
                                    unsigned short* hi, unsigned short* lo) {
  float t32 = w * rcp32;
  float n32 = rintf(t32);
  double n;
  if (__builtin_expect(fabsf(fabsf(t32 - n32) - 0.5f) < 1e-4f, 0)) {
    n = rint((double)w / scale_d);           // exact decision at the boundary
  } else {
    n = (double)n32;
  }
  n = fmin(fmax(n, -7.0), 7.0);
  float qf = (float)(n * scale_d);
  unsigned short h = f32_to_bf16_rne(qf);
  *hi = h;
  *lo = f32_to_bf16_rne(qf - bf16_bits_to_f32(h));
}

// ---------------- Kernel 1: quantize B -> split Bq^T (bf16 hi/lo planes) ----
// 64 blocks x 256 threads x 4 elems (float4); group of 32 = 8 consecutive
// lanes' float4s (aligned since 256 % 8 == 0).
__global__ __launch_bounds__(256) void quantB_kernel(
    const float* __restrict__ B,
    unsigned short* __restrict__ BqT_hi, unsigned short* __restrict__ BqT_lo) {
  int e4 = blockIdx.x * 256 + threadIdx.x;   // 0..16383
  int e  = e4 * 4;
  int r  = e >> 10;                          // row in [0,64)
  int c  = e & 1023;                         // col in [0,1024), 4 consecutive
  float4 w = *(const float4*)(B + e);
  float a = fmaxf(fmaxf(fabsf(w.x), fabsf(w.y)), fmaxf(fabsf(w.z), fabsf(w.w)));
  a = fmaxf(a, __shfl_xor(a, 1));
  a = fmaxf(a, __shfl_xor(a, 2));
  a = fmaxf(a, __shfl_xor(a, 4));
  double sc = fmax((double)a, 1e-8) / 7.0;
  float rcp = 1.0f / (float)sc;
  float wv[4] = {w.x, w.y, w.z, w.w};
  #pragma unroll
  for (int j = 0; j < 4; ++j) {
    unsigned short hi, lo;
    quant_elem_g(wv[j], rcp, sc, &hi, &lo);
    BqT_hi[(c + j) * R_DIM + r] = hi;
    BqT_lo[(c + j) * R_DIM + r] = lo;
  }
}

// ---------------- Kernel 2: A-quant ONCE, loop 2 col-slices -----------------
__global__ __launch_bounds__(256, 4) void gemm_kernel(
    const float* __restrict__ U, const int* __restrict__ ids,
    const unsigned short* __restrict__ BqT_hi, const unsigned short* __restrict__ BqT_lo,
    float* __restrict__ out) {
  // B planes (2 x 18KB) overlaid with the out-transpose buffer (33KB).
  // 36864B -> 4 blocks/CU; grid 1024 = exactly co-resident.
  __shared__ char smem[2 * BN * LDS_STRIDE * 2];
  unsigned short* bt_hi = (unsigned short*)smem;
  unsigned short* bt_lo = bt_hi + BN * LDS_STRIDE;
  float* ot = (float*)smem;

  const int tid  = threadIdx.x;
  const int lane = tid & 63;
  const int wave = tid >> 6;
  const int bx   = blockIdx.x;
  const int grp  = bx & 3;     // 4 slice-groups x 2 slices = 8 col-slices;
  const int mb   = bx >> 2;    //  consecutive bx (same mb) -> 4 diff XCDs
  const int m0   = mb * BM + wave * 16;
  const int koff  = (lane >> 4) * 8;         // k-chunk of 8 within the 32-group
  const int nlane = lane & 15;

  // --- A gather (in flight under quant VALU) -------------------------------
  const float* urow = U + (size_t)ids[m0 + nlane] * R_DIM;
  float4 wr[2][2];
  #pragma unroll
  for (int s = 0; s < 2; ++s) {
    wr[s][0] = *(const float4*)(urow + s * 32 + koff);
    wr[s][1] = *(const float4*)(urow + s * 32 + koff + 4);
  }

  // --- guarded-quantize A fragments ONCE (reused for both slices) ----------
  // Lane holds elems s*32+koff..+8 of its row; lanes {l&15 fixed, l>>4
  // varying} hold one 32-elem quant group -> amax via shfl_xor 16/32.
  bf16x8 ah[2], al[2];
  #pragma unroll
  for (int s = 0; s < 2; ++s) {
    float4 w0 = wr[s][0], w1 = wr[s][1];
    float wv[8] = {w0.x, w0.y, w0.z, w0.w, w1.x, w1.y, w1.z, w1.w};
    float a = 0.0f;
    #pragma unroll
    for (int j = 0; j < 8; ++j) a = fmaxf(a, fabsf(wv[j]));
    a = fmaxf(a, __shfl_xor(a, 16));
    a = fmaxf(a, __shfl_xor(a, 32));
    const double sc = fmax((double)a, 1e-8) / 7.0;
    const float rcp = 1.0f / (float)sc;
    union { unsigned short s8[8]; bf16x8 b; } uh, ul;
    #pragma unroll
    for (int j = 0; j < 8; ++j) {
      unsigned short hi, lo;
      quant_elem_g(wv[j], rcp, sc, &hi, &lo);
      uh.s8[j] = hi;
      ul.s8[j] = lo;
    }
    ah[s] = uh.b;
    al[s] = ul.b;
  }

  // --- loop over this block's 2 col-slices ---------------------------------
  #pragma unroll
  for (int sl = 0; sl < NSLICE; ++sl) {
    const int n0 = (grp * NSLICE + sl) * BN;

    if (sl > 0) __syncthreads();   // prior slice's ot reads complete

    // stage Bq^T slice (rows n0..n0+127 = one contiguous 16KB span/plane)
    {
      const uint4* src_hi = (const uint4*)(BqT_hi + (size_t)n0 * R_DIM);
      const uint4* src_lo = (const uint4*)(BqT_lo + (size_t)n0 * R_DIM);
      #pragma unroll
      for (int it = 0; it < 4; ++it) {
        int c = tid + it * 256;              // 16B chunk index, 0..1023
        int row = c >> 3, off = c & 7;
        *(uint4*)&bt_hi[row * LDS_STRIDE + off * 8] = src_hi[c];
        *(uint4*)&bt_lo[row * LDS_STRIDE + off * 8] = src_lo[c];
      }
    }
    __syncthreads();

    // MFMA: 8 n-frags x 2 k-steps x {hi*hi, hi*lo, lo*hi}
    f32x4 acc[8];
    #pragma unroll
    for (int nf = 0; nf < 8; ++nf) acc[nf] = (f32x4){0.f, 0.f, 0.f, 0.f};

    #pragma unroll
    for (int nf = 0; nf < 8; ++nf) {
      #pragma unroll
      for (int s = 0; s < 2; ++s) {
        const int boff = (nf * 16 + nlane) * LDS_STRIDE + s * 32 + koff;
        union { uint4 u; bf16x8 b; } bh, bl;
        bh.u = *(const uint4*)&bt_hi[boff];
        bl.u = *(const uint4*)&bt_lo[boff];
        acc[nf] = __builtin_amdgcn_mfma_f32_16x16x32_bf16(ah[s], bh.b, acc[nf], 0, 0, 0);
        acc[nf] = __builtin_amdgcn_mfma_f32_16x16x32_bf16(ah[s], bl.b, acc[nf], 0, 0, 0);
        acc[nf] = __builtin_amdgcn_mfma_f32_16x16x32_bf16(al[s], bh.b, acc[nf], 0, 0, 0);
      }
    }

    __syncthreads();   // done reading B planes; reuse smem for out-transpose

    // per-wave LDS transpose + coalesced nt stores
    float* wp = ot + wave * 16 * OT_STRIDE;
    {
      const int r0 = (lane >> 4) << 2;       // 0,4,8,12
      #pragma unroll
      for (int nf = 0; nf < 8; ++nf) {
        #pragma unroll
        for (int i = 0; i < 4; ++i) {
          wp[(r0 + i) * OT_STRIDE + nlane + nf * 16] = acc[nf][i];
        }
      }
    }
    #pragma unroll
    for (int j = 0; j < 8; ++j) {
      const int row = j * 2 + (lane >> 5);   // 0..15
      f32x4 v = *(const f32x4*)&wp[row * OT_STRIDE + (lane & 31) * 4];
      // 32 lanes x 16B = one contiguous 512B row segment; nt write-once stream
      __builtin_nontemporal_store(v,
          (f32x4*)&out[(size_t)(m0 + row) * D_DIM + n0 + (lane & 31) * 4]);
    }
  }
}

extern "C" void kernel_launch(void* const* d_in, const int* in_sizes, int n_in,
                              void* d_out, int out_size, void* d_ws, size_t ws_size,
                              hipStream_t stream) {
  const float* U   = (const float*)d_in[0];
  const float* B   = (const float*)d_in[1];
  const int*   ids = (const int*)d_in[2];
  float* out = (float*)d_out;

  unsigned short* BqT_hi = (unsigned short*)d_ws;                       // 128 KB
  unsigned short* BqT_lo = BqT_hi + R_DIM * D_DIM;                      // 128 KB

  quantB_kernel<<<(R_DIM * D_DIM) / (256 * 4), 256, 0, stream>>>(B, BqT_hi, BqT_lo);
  gemm_kernel<<<(N_IDS / BM) * (D_DIM / (BN * NSLICE)), 256, 0, stream>>>(
      U, ids, BqT_hi, BqT_lo, out);
}